// Round 2
// baseline (536.761 us; speedup 1.0000x reference)
//
#include <hip/hip_runtime.h>

// SimpleAttention v2: register-tiled PV (8i x 8d per thread), p via bf16 LDS.
// B=16, C=3072, T=2048, n=32.
// out[b, i*64+d, t] = sum_j softmax_j(a[i][j]) * ctx[j][d]   (per b,t)
// attentions[b,i,j,t] = p[j] + (i==j ? 0 : p[j+32])

typedef unsigned short ushort_t;
typedef unsigned int   uint_t;

constexpr int Bq = 16, Cq = 3072, Tq = 2048;
constexpr int TT = 8;                    // t-tile
constexpr int TILES = Tq / TT;           // 256
constexpr int NBLK = Bq * TILES;         // 4096
constexpr int NPI = 40;                  // plds i-stride (ushorts): 32 + 8 pad (80 B rows)
constexpr int NPD = 68;                  // clds d-stride (floats): 64 + 4 pad (272 B rows)
constexpr size_t ATT_OFF = (size_t)Bq * 2048 * Tq;

__global__ __launch_bounds__(256) void attn_v2(const float* __restrict__ x,
                                               const float* __restrict__ xi,
                                               float* __restrict__ out)
{
    __shared__ __align__(16) ushort_t plds[64 * TT * NPI];  // [j][tl][i]  40960 B
    __shared__ __align__(16) float    clds[8 * TT * NPD];   // [jj][tl][d] 17408 B

    // XCD-bijective swizzle: blocks on the same XCD get consecutive tiles
    unsigned lin = blockIdx.x;
    unsigned swz = (lin & 7u) * (NBLK / 8) + (lin >> 3);
    const int b    = (int)(swz >> 8);            // / TILES
    const int tile = (int)(swz & (TILES - 1));

    const int tl = threadIdx.x & (TT - 1);       // t within tile
    const int sl = threadIdx.x >> 3;             // 0..31
    const int t  = tile * TT + tl;

    const float* xb  = x  + (size_t)b * Cq * Tq + t;
    const float* xib = xi + (size_t)b * Cq * Tq + t;

    // ---- phase A: softmax of row i=sl, in registers ----
    float p[64];
    {
        const int base = sl * 96;
#pragma unroll
        for (int j = 0; j < 32; ++j) p[j]      = xb [(size_t)(base + j) * Tq];
#pragma unroll
        for (int j = 0; j < 32; ++j) p[j + 32] = xib[(size_t)(base + j) * Tq];
        float m = p[0];
#pragma unroll
        for (int j = 1; j < 64; ++j) m = fmaxf(m, p[j]);
        float s = 0.f;
#pragma unroll
        for (int j = 0; j < 64; ++j) { p[j] = __expf(p[j] - m); s += p[j]; }
        const float inv = 1.f / s;
#pragma unroll
        for (int j = 0; j < 64; ++j) p[j] *= inv;
    }

    // ---- attentions output (exact f32 from registers) ----
    {
        float* ao = out + ATT_OFF + ((size_t)(b * 32 + sl) * 32) * Tq + t;
#pragma unroll
        for (int j = 0; j < 32; ++j) {
            float v = p[j] + ((j == sl) ? 0.f : p[j + 32]);
            __builtin_nontemporal_store(v, &ao[(size_t)j * Tq]);
        }
    }

    // ---- p -> LDS as bf16 (RNE) ----
#pragma unroll
    for (int j = 0; j < 64; ++j) {
        uint_t bits = __float_as_uint(p[j]);
        ushort_t u = (ushort_t)((bits + 0x7fffu + ((bits >> 16) & 1u)) >> 16);
        plds[(j * TT + tl) * NPI + sl] = u;
    }

    // ---- phase B: thread = (tl, ig, dg), computes i in [ig*8,+8), d in [dg*8,+8) ----
    const int ig = sl & 3, dg = sl >> 2;
    const float* xb0  = x  + (size_t)b * Cq * Tq + (size_t)tile * TT;
    const float* xib0 = xi + (size_t)b * Cq * Tq + (size_t)tile * TT;

    float acc[8][8];
#pragma unroll
    for (int r = 0; r < 8; ++r)
#pragma unroll
        for (int c = 0; c < 8; ++c) acc[r][c] = 0.f;

    float rv[16];
    auto pf = [&](int jc) {
#pragma unroll
        for (int k = 0; k < 16; ++k) {
            int d = ((int)(threadIdx.x >> 3) & 31) + 32 * (k & 1);
            int j = jc * 8 + (k >> 1);
            int cch = (j < 32) ? (j * 96 + 32 + d) : ((j - 32) * 96 + 32 + d);
            const float* srcp = (j < 32) ? xb0 : xib0;
            rv[k] = srcp[(size_t)cch * Tq + (int)(threadIdx.x & 7)];
        }
    };
    auto st = [&]() {
#pragma unroll
        for (int k = 0; k < 16; ++k) {
            int d = ((int)(threadIdx.x >> 3) & 31) + 32 * (k & 1);
            int jj = k >> 1;
            clds[(jj * TT + (int)(threadIdx.x & 7)) * NPD + d] = rv[k];
        }
    };

    pf(0);
    __syncthreads();                       // plds visible to all
    for (int jc = 0; jc < 8; ++jc) {
        st();                              // rv -> clds (waits vmcnt via data dep)
        __syncthreads();                   // clds ready
        if (jc < 7) pf(jc + 1);            // prefetch next chunk under compute
        const int jb = jc * 8;
#pragma unroll
        for (int jj = 0; jj < 8; ++jj) {
            const int4 pv = *reinterpret_cast<const int4*>(
                &plds[((jb + jj) * TT + tl) * NPI + ig * 8]);
            float pfv[8];
            pfv[0] = __uint_as_float(((uint_t)pv.x) << 16);
            pfv[1] = __uint_as_float(((uint_t)pv.x) & 0xffff0000u);
            pfv[2] = __uint_as_float(((uint_t)pv.y) << 16);
            pfv[3] = __uint_as_float(((uint_t)pv.y) & 0xffff0000u);
            pfv[4] = __uint_as_float(((uint_t)pv.z) << 16);
            pfv[5] = __uint_as_float(((uint_t)pv.z) & 0xffff0000u);
            pfv[6] = __uint_as_float(((uint_t)pv.w) << 16);
            pfv[7] = __uint_as_float(((uint_t)pv.w) & 0xffff0000u);
            const float4 cv0 = *reinterpret_cast<const float4*>(
                &clds[(jj * TT + tl) * NPD + dg * 8]);
            const float4 cv1 = *reinterpret_cast<const float4*>(
                &clds[(jj * TT + tl) * NPD + dg * 8 + 4]);
#pragma unroll
            for (int r = 0; r < 8; ++r) {
                acc[r][0] += pfv[r] * cv0.x;
                acc[r][1] += pfv[r] * cv0.y;
                acc[r][2] += pfv[r] * cv0.z;
                acc[r][3] += pfv[r] * cv0.w;
                acc[r][4] += pfv[r] * cv1.x;
                acc[r][5] += pfv[r] * cv1.y;
                acc[r][6] += pfv[r] * cv1.z;
                acc[r][7] += pfv[r] * cv1.w;
            }
        }
        __syncthreads();                   // compute reads done before next st
    }

    // ---- stores: out[b, (ig*8+r)*64 + dg*8+c, t] ----
    float* ob = out + (size_t)b * 2048 * Tq + t;
#pragma unroll
    for (int r = 0; r < 8; ++r) {
#pragma unroll
        for (int c = 0; c < 8; ++c) {
            int ch = (ig * 8 + r) * 64 + dg * 8 + c;
            __builtin_nontemporal_store(acc[r][c], &ob[(size_t)ch * Tq]);
        }
    }
}

extern "C" void kernel_launch(void* const* d_in, const int* in_sizes, int n_in,
                              void* d_out, int out_size, void* d_ws, size_t ws_size,
                              hipStream_t stream) {
    const float* x  = (const float*)d_in[0];
    const float* xi = (const float*)d_in[1];
    float* out = (float*)d_out;
    attn_v2<<<dim3(NBLK), dim3(256), 0, stream>>>(x, xi, out);
}